// Round 6
// baseline (317.694 us; speedup 1.0000x reference)
//
#include <hip/hip_runtime.h>
#include <hip/hip_bf16.h>
#include <cmath>

// Problem constants (Qwen3 MoE block)
constexpr int T = 2048;   // tokens (B*S)
constexpr int H = 1024;   // hidden
constexpr int I = 768;    // intermediate
constexpr int E = 16;     // experts
constexpr int WMAX = 48;  // max worklist items at M=128 (sum ceil(n_e/128) <= 48)

typedef short short8 __attribute__((ext_vector_type(8)));
typedef float f32x4  __attribute__((ext_vector_type(4)));

__device__ __forceinline__ short f2bf(float f) {
    __hip_bfloat16 h = __float2bfloat16(f);   // RNE
    return *reinterpret_cast<short*>(&h);
}

__device__ __forceinline__ short8 pack8(float4 a, float4 b) {
    short8 v = {f2bf(a.x), f2bf(a.y), f2bf(a.z), f2bf(a.w),
                f2bf(b.x), f2bf(b.y), f2bf(b.z), f2bf(b.w)};
    return v;
}

// XOR-swizzled LDS index (units: shorts). Row stride 32 bf16 = 64 B.
// Proven conflict-free in round 2 (SQ_LDS_BANK_CONFLICT = 0).
__device__ __forceinline__ int sw(int r, int kg) {
    return r * 32 + (((kg + (r >> 1)) & 3) << 3);
}

// ------------------------------------------------------------------
// Router (+ fused x fp32->bf16 convert): block = 16 tokens.
// Thread layout A: (token, expert) fp32 dot; layout B: each thread
// converts a 64-float slice of the same 16 rows (8 short8 stores).
// ------------------------------------------------------------------
__global__ __launch_bounds__(256) void router_kernel(
    const float* __restrict__ x,     // [T,H]
    const float* __restrict__ gw,    // [E,H]
    int* __restrict__ cnt,           // [E]
    int* __restrict__ entries,       // [E,T]  value = t*2 + k
    float* __restrict__ wlist,       // [E,T]
    short* __restrict__ xb)          // [T,H] bf16 out
{
    const int tid = threadIdx.x;
    const int tl = tid & 15, e = tid >> 4;
    const int t = blockIdx.x * 16 + tl;

    const float4* xr = (const float4*)(x + (size_t)t * H);
    const float4* gr = (const float4*)(gw + (size_t)e * H);
    float s0 = 0.f, s1 = 0.f;
    #pragma unroll 8
    for (int q = 0; q < 256; q += 2) {
        float4 a = xr[q],     b = gr[q];
        float4 c = xr[q + 1], d = gr[q + 1];
        s0 += a.x * b.x + a.y * b.y + a.z * b.z + a.w * b.w;
        s1 += c.x * d.x + c.y * d.y + c.z * d.z + c.w * d.w;
    }

    // fused x -> bf16: thread (row16, c16) converts 64 floats
    // (16 float4 reads -> 8 short8 stores; round-5 bug was j<4 = half)
    {
        const int row16 = tid >> 4, c16 = tid & 15;
        const float4* src = (const float4*)(x + (size_t)(blockIdx.x * 16 + row16) * H + c16 * 64);
        short* dst = xb + (size_t)(blockIdx.x * 16 + row16) * H + c16 * 64;
        #pragma unroll
        for (int j = 0; j < 8; ++j)
            *(short8*)(dst + j * 8) = pack8(src[2 * j], src[2 * j + 1]);
    }

    __shared__ float lg[16][17];
    lg[tl][e] = s0 + s1;
    __syncthreads();

    if (tid < 16) {
        int tk = blockIdx.x * 16 + tid;
        float v1 = -3.0e38f, v2 = -3.0e38f;
        int i1 = 0, i2 = 0;
        #pragma unroll
        for (int k = 0; k < E; ++k) {
            float v = lg[tid][k];
            if (v > v1) { v2 = v1; i2 = i1; v1 = v; i1 = k; }
            else if (v > v2) { v2 = v; i2 = k; }
        }
        // renormalized top-2 softmax == softmax over the two winning logits
        float w1 = 1.f / (1.f + expf(v2 - v1));
        float w2 = 1.f - w1;
        int p = atomicAdd(&cnt[i1], 1);
        entries[i1 * T + p] = tk * 2;
        wlist[i1 * T + p] = w1;
        p = atomicAdd(&cnt[i2], 1);
        entries[i2 * T + p] = tk * 2 + 1;
        wlist[i2 * T + p] = w2;
    }
}

// ------------------------------------------------------------------
// Work-list builder: flat (expert, t0) items, M-tile = 128.
// ------------------------------------------------------------------
__global__ void build_worklist(const int* __restrict__ cnt,
                               int2* __restrict__ items,
                               int* __restrict__ nitems)
{
    if (threadIdx.x == 0) {
        int c = 0;
        for (int e = 0; e < E; ++e) {
            int n = cnt[e];
            for (int t0 = 0; t0 < n; t0 += 128) items[c++] = make_int2(e, t0);
        }
        *nitems = c;
    }
}

// ------------------------------------------------------------------
// Grouped gate/up GEMM + SwiGLU, bf16 MFMA. Tile M=128 x N=32, BK=32.
// LDS double-buffered, ONE barrier per K-iter; next chunk's global
// loads issue before the MFMA phase (a full iteration of latency
// budget). Waves m-split (32 rows each); gate staged by waves 0-1,
// up by waves 2-3; SwiGLU wave-local.
// ------------------------------------------------------------------
__global__ __launch_bounds__(256) void gateup_mfma(
    const short* __restrict__ xb,      // [T,H] bf16
    const float* __restrict__ gate_p,  // [E,I,H] f32
    const float* __restrict__ up_p,    // [E,I,H] f32
    const int* __restrict__ cnt,
    const int* __restrict__ entries,
    const int* __restrict__ nitems,
    const int2* __restrict__ items,
    short* __restrict__ hmid)          // [2T,I] bf16, row = slot = t*2+k
{
    if (blockIdx.x >= *nitems) return;
    const int e  = items[blockIdx.x].x;
    const int t0 = items[blockIdx.x].y;
    const int n  = cnt[e];
    const int i0 = blockIdx.y * 32;

    __shared__ short Xs[2][128 * 32];
    __shared__ short Gs[2][32 * 32];
    __shared__ short Us[2][32 * 32];
    __shared__ int toks[128];

    const int tid = threadIdx.x;
    if (tid < 128) {
        int r = t0 + tid;
        toks[tid] = (r < n) ? entries[e * T + r] : -1;
    }
    __syncthreads();

    const int lane = tid & 63, wave = tid >> 6;
    const int m16 = lane & 15, q = lane >> 4;
    const int wm = wave * 32;

    // staging: X = 512 16B-slots (2/thread); weights = 256 slots
    const int sr = tid >> 2, skg = tid & 3;
    const int xt0 = toks[sr], xt1 = toks[64 + sr];
    const short* xsrc0 = xb + (size_t)((xt0 >= 0 ? xt0 : 0) >> 1) * H + skg * 8;
    const short* xsrc1 = xb + (size_t)((xt1 >= 0 ? xt1 : 0) >> 1) * H + skg * 8;
    const int wt = tid >> 7;                 // 0 = gate (waves 0-1), 1 = up
    const int st = tid & 127, wrr = st >> 2, wkg = st & 3;
    const float* wsrc = (wt ? up_p : gate_p)
        + (size_t)e * I * H + (size_t)(i0 + wrr) * H + wkg * 8;

    f32x4 accg[2][2], accu[2][2];
    #pragma unroll
    for (int a = 0; a < 2; ++a)
        #pragma unroll
        for (int b = 0; b < 2; ++b) {
            accg[a][b] = (f32x4){0.f, 0.f, 0.f, 0.f};
            accu[a][b] = (f32x4){0.f, 0.f, 0.f, 0.f};
        }

    // prologue: chunk 0 -> buf 0
    {
        short8 x0 = *(const short8*)xsrc0;
        short8 x1 = *(const short8*)xsrc1;
        float4 wa = *(const float4*)wsrc, wb = *(const float4*)(wsrc + 4);
        *(short8*)&Xs[0][sw(sr, skg)]      = x0;
        *(short8*)&Xs[0][sw(64 + sr, skg)] = x1;
        short8 pw = pack8(wa, wb);
        if (wt == 0) *(short8*)&Gs[0][sw(wrr, wkg)] = pw;
        else         *(short8*)&Us[0][sw(wrr, wkg)] = pw;
    }
    __syncthreads();

    constexpr int NIT = H / 32;
    for (int it = 0; it < NIT; ++it) {
        const int cur = it & 1, nxt = cur ^ 1;
        const int kn = (it + 1 < NIT) ? (it + 1) * 32 : 0;
        // issue next chunk's loads (in flight during MFMA)
        short8 nx0 = *(const short8*)(xsrc0 + kn);
        short8 nx1 = *(const short8*)(xsrc1 + kn);
        float4 nwa = *(const float4*)(wsrc + kn), nwb = *(const float4*)(wsrc + kn + 4);

        // MFMA on current buffer
        short8 af0 = *(const short8*)&Xs[cur][sw(wm + m16, q)];
        short8 af1 = *(const short8*)&Xs[cur][sw(wm + 16 + m16, q)];
        short8 bg0 = *(const short8*)&Gs[cur][sw(m16, q)];
        short8 bg1 = *(const short8*)&Gs[cur][sw(16 + m16, q)];
        short8 bu0 = *(const short8*)&Us[cur][sw(m16, q)];
        short8 bu1 = *(const short8*)&Us[cur][sw(16 + m16, q)];
        accg[0][0] = __builtin_amdgcn_mfma_f32_16x16x32_bf16(af0, bg0, accg[0][0], 0, 0, 0);
        accg[1][0] = __builtin_amdgcn_mfma_f32_16x16x32_bf16(af1, bg0, accg[1][0], 0, 0, 0);
        accg[0][1] = __builtin_amdgcn_mfma_f32_16x16x32_bf16(af0, bg1, accg[0][1], 0, 0, 0);
        accg[1][1] = __builtin_amdgcn_mfma_f32_16x16x32_bf16(af1, bg1, accg[1][1], 0, 0, 0);
        accu[0][0] = __builtin_amdgcn_mfma_f32_16x16x32_bf16(af0, bu0, accu[0][0], 0, 0, 0);
        accu[1][0] = __builtin_amdgcn_mfma_f32_16x16x32_bf16(af1, bu0, accu[1][0], 0, 0, 0);
        accu[0][1] = __builtin_amdgcn_mfma_f32_16x16x32_bf16(af0, bu1, accu[0][1], 0, 0, 0);
        accu[1][1] = __builtin_amdgcn_mfma_f32_16x16x32_bf16(af1, bu1, accu[1][1], 0, 0, 0);

        // store next chunk into the other buffer
        *(short8*)&Xs[nxt][sw(sr, skg)]      = nx0;
        *(short8*)&Xs[nxt][sw(64 + sr, skg)] = nx1;
        short8 pw = pack8(nwa, nwb);
        if (wt == 0) *(short8*)&Gs[nxt][sw(wrr, wkg)] = pw;
        else         *(short8*)&Us[nxt][sw(wrr, wkg)] = pw;
        __syncthreads();
    }

    // epilogue: SwiGLU, scalar bf16 stores
    #pragma unroll
    for (int mi = 0; mi < 2; ++mi)
        #pragma unroll
        for (int ni = 0; ni < 2; ++ni)
            #pragma unroll
            for (int j = 0; j < 4; ++j) {
                int row = wm + mi * 16 + q * 4 + j;
                int slot = toks[row];
                if (slot < 0) continue;
                float g = accg[mi][ni][j];
                float u = accu[mi][ni][j];
                float hv = g / (1.f + expf(-g)) * u;
                int col = i0 + ni * 16 + m16;
                ((unsigned short*)hmid)[(size_t)slot * I + col] = (unsigned short)f2bf(hv);
            }
}

// ------------------------------------------------------------------
// Grouped down GEMM, bf16 MFMA. Tile M=128 x N=64, BK=32, LDS
// double-buffer, one barrier/iter. Waves m-split. f32 atomic combine.
// ------------------------------------------------------------------
__global__ __launch_bounds__(256) void down_mfma(
    const short* __restrict__ hmid,    // [2T,I] bf16
    const float* __restrict__ down_p,  // [E,H,I] f32
    const int* __restrict__ cnt,
    const int* __restrict__ entries,
    const float* __restrict__ wlist,
    const int* __restrict__ nitems,
    const int2* __restrict__ items,
    float* __restrict__ out)           // [T,H], pre-zeroed
{
    if (blockIdx.x >= *nitems) return;
    const int e  = items[blockIdx.x].x;
    const int t0 = items[blockIdx.x].y;
    const int n  = cnt[e];
    const int h0 = blockIdx.y * 64;

    __shared__ short As[2][128 * 32];
    __shared__ short Bs[2][64 * 32];
    __shared__ int toks[128];
    __shared__ float wr[128];

    const int tid = threadIdx.x;
    if (tid < 128) {
        int r = t0 + tid;
        bool v = (r < n);
        toks[tid] = v ? entries[e * T + r] : -1;
        wr[tid]   = v ? wlist[e * T + r] : 0.f;
    }
    __syncthreads();

    const int lane = tid & 63, wave = tid >> 6;
    const int m16 = lane & 15, q = lane >> 4;
    const int wm = wave * 32;

    const int sr = tid >> 2, skg = tid & 3;
    const int at0 = toks[sr], at1 = toks[64 + sr];
    const short* asrc0 = hmid + (size_t)(at0 >= 0 ? at0 : 0) * I + skg * 8;
    const short* asrc1 = hmid + (size_t)(at1 >= 0 ? at1 : 0) * I + skg * 8;
    const float* bsrc = down_p + (size_t)e * H * I + (size_t)(h0 + sr) * I + skg * 8;

    f32x4 acc[2][4];
    #pragma unroll
    for (int a = 0; a < 2; ++a)
        #pragma unroll
        for (int b = 0; b < 4; ++b)
            acc[a][b] = (f32x4){0.f, 0.f, 0.f, 0.f};

    // prologue: chunk 0 -> buf 0
    {
        short8 a0 = *(const short8*)asrc0;
        short8 a1 = *(const short8*)asrc1;
        float4 ba = *(const float4*)bsrc, bb = *(const float4*)(bsrc + 4);
        *(short8*)&As[0][sw(sr, skg)]      = a0;
        *(short8*)&As[0][sw(64 + sr, skg)] = a1;
        *(short8*)&Bs[0][sw(sr, skg)] = pack8(ba, bb);
    }
    __syncthreads();

    constexpr int NIT = I / 32;
    for (int it = 0; it < NIT; ++it) {
        const int cur = it & 1, nxt = cur ^ 1;
        const int kn = (it + 1 < NIT) ? (it + 1) * 32 : 0;
        short8 na0 = *(const short8*)(asrc0 + kn);
        short8 na1 = *(const short8*)(asrc1 + kn);
        float4 nba = *(const float4*)(bsrc + kn), nbb = *(const float4*)(bsrc + kn + 4);

        short8 af0 = *(const short8*)&As[cur][sw(wm + m16, q)];
        short8 af1 = *(const short8*)&As[cur][sw(wm + 16 + m16, q)];
        #pragma unroll
        for (int ni = 0; ni < 4; ++ni) {
            short8 bfr = *(const short8*)&Bs[cur][sw(ni * 16 + m16, q)];
            acc[0][ni] = __builtin_amdgcn_mfma_f32_16x16x32_bf16(af0, bfr, acc[0][ni], 0, 0, 0);
            acc[1][ni] = __builtin_amdgcn_mfma_f32_16x16x32_bf16(af1, bfr, acc[1][ni], 0, 0, 0);
        }

        *(short8*)&As[nxt][sw(sr, skg)]      = na0;
        *(short8*)&As[nxt][sw(64 + sr, skg)] = na1;
        *(short8*)&Bs[nxt][sw(sr, skg)] = pack8(nba, nbb);
        __syncthreads();
    }

    #pragma unroll
    for (int mi = 0; mi < 2; ++mi)
        #pragma unroll
        for (int ni = 0; ni < 4; ++ni)
            #pragma unroll
            for (int j = 0; j < 4; ++j) {
                int row = wm + mi * 16 + q * 4 + j;
                int slot = toks[row];
                if (slot < 0) continue;
                int t = slot >> 1;
                float w = wr[row];
                int col = h0 + ni * 16 + m16;
                atomicAdd(&out[(size_t)t * H + col], w * acc[mi][ni][j]);
            }
}

extern "C" void kernel_launch(void* const* d_in, const int* in_sizes, int n_in,
                              void* d_out, int out_size, void* d_ws, size_t ws_size,
                              hipStream_t stream) {
    const float* x  = (const float*)d_in[0];   // [1,2048,1024]
    const float* gw = (const float*)d_in[1];   // [16,1024]
    const float* gp = (const float*)d_in[2];   // [16,768,1024]
    const float* up = (const float*)d_in[3];   // [16,768,1024]
    const float* dp = (const float*)d_in[4];   // [16,1024,768]
    float* out = (float*)d_out;

    char* ws = (char*)d_ws;
    int*   cnt     = (int*)ws;                       // 16 ints
    int*   nitems  = (int*)(ws + 64);
    int2*  items   = (int2*)(ws + 128);              // <=48 items
    int*   entries = (int*)(ws + 2048);              // E*T ints   (128 KB)
    float* wlist   = (float*)(ws + 2048 + 131072);   // E*T floats (128 KB)
    short* xb      = (short*)(ws + 2048 + 262144);   // T*H bf16   (4 MB)
    short* hmid    = xb + (size_t)T * H;             // 2T*I bf16  (6 MB)
    // total ~10.7 MB (round 1 proved ws >= 12.7 MB)

    hipMemsetAsync(ws, 0, 2048, stream);
    hipMemsetAsync(out, 0, (size_t)T * H * sizeof(float), stream);

    router_kernel<<<T / 16, 256, 0, stream>>>(x, gw, cnt, entries, wlist, xb);
    build_worklist<<<1, 64, 0, stream>>>(cnt, items, nitems);
    gateup_mfma<<<dim3(WMAX, I / 32), 256, 0, stream>>>(
        xb, gp, up, cnt, entries, nitems, items, hmid);
    down_mfma<<<dim3(WMAX, H / 64), 256, 0, stream>>>(
        hmid, dp, cnt, entries, wlist, nitems, items, out);
}